// Round 6
// baseline (3555.624 us; speedup 1.0000x reference)
//
#include <hip/hip_runtime.h>
#include <hip/hip_bf16.h>

typedef unsigned short u16;
typedef unsigned long long u64;
typedef short short8 __attribute__((ext_vector_type(8)));
typedef float floatx4 __attribute__((ext_vector_type(4)));

#define BATCH 64
#define SEQT  256
#define DDIM  1024
#define HDIM  1024
#define GDIM  4096          // 4H
#define MROWS 16384         // B*T
#define BH    (BATCH * HDIM)   // 65536 elems = 128 KB bf16

// ---------- helpers ----------
__device__ __forceinline__ u16 f2bf(float f) {
  unsigned u = __builtin_bit_cast(unsigned, f);
  u += 0x7fffu + ((u >> 16) & 1u);
  return (u16)(u >> 16);
}
__device__ __forceinline__ float bf2f(u16 v) {
  unsigned u = ((unsigned)v) << 16;
  return __builtin_bit_cast(float, u);
}
__device__ __forceinline__ float xz2f(float v) { return v; }
__device__ __forceinline__ float xz2f(u16 v) { return bf2f(v); }

template <typename T> __device__ __forceinline__ T f2xz(float v);
template <> __device__ __forceinline__ float f2xz<float>(float v) { return v; }
template <> __device__ __forceinline__ u16 f2xz<u16>(float v) { return f2bf(v); }

__device__ __forceinline__ float sigm(float x) { return 1.0f / (1.0f + __expf(-x)); }
__device__ __forceinline__ float tanh_(float x) {
  float a = __expf(2.0f * fabsf(x));      // inf-safe: a=inf -> r=1
  float r = 1.0f - 2.0f / (a + 1.0f);
  return x >= 0.0f ? r : -r;
}

__device__ __forceinline__ void async16(const void* g, void* l) {
  __builtin_amdgcn_global_load_lds(
      (const __attribute__((address_space(1))) unsigned int*)g,
      (__attribute__((address_space(3))) unsigned int*)l, 16, 0, 0);
}

// agent-scope (LLC-coherent) store for the h hand-off (write-around local L2,
// lands at the memory-side LLC = the coherence point)
__device__ __forceinline__ void st_agent(unsigned* p, unsigned v) {
  __hip_atomic_store(p, v, __ATOMIC_RELAXED, __HIP_MEMORY_SCOPE_AGENT);
}

// Fence-free grid barrier (128 wgs total: words [0,64) dir0, [64,128) dir1).
__device__ __forceinline__ void grid_barrier(unsigned* bar_, int wdg, int l, unsigned epoch) {
  __syncthreads();
  if (threadIdx.x == 0)
    __hip_atomic_store(bar_ + wdg, epoch, __ATOMIC_RELAXED, __HIP_MEMORY_SCOPE_AGENT);
  if (threadIdx.x < 64) {
    unsigned a, b;
    do {
      __builtin_amdgcn_s_sleep(2);
      a = __hip_atomic_load(bar_ + l,      __ATOMIC_RELAXED, __HIP_MEMORY_SCOPE_AGENT);
      b = __hip_atomic_load(bar_ + 64 + l, __ATOMIC_RELAXED, __HIP_MEMORY_SCOPE_AGENT);
    } while (!__all(a >= epoch && b >= epoch));
  }
  __syncthreads();
}

// ---------- kernel 1: x fp32 -> bf16 ----------
__global__ __launch_bounds__(256) void k_cvt_x(const float* __restrict__ in,
                                               u16* __restrict__ out) {
  long i = ((long)blockIdx.x * 256 + threadIdx.x) * 4;
  float4 v = *(const float4*)(in + i);
  u16 o0 = f2bf(v.x), o1 = f2bf(v.y), o2 = f2bf(v.z), o3 = f2bf(v.w);
  unsigned lo = (unsigned)o0 | ((unsigned)o1 << 16);
  unsigned hi = (unsigned)o2 | ((unsigned)o3 << 16);
  uint2 p; p.x = lo; p.y = hi;
  *(uint2*)(out + i) = p;
}

// ---------- kernel 2: transpose-convert [1024][4096] fp32 -> [4096][1024] bf16 ----------
__global__ __launch_bounds__(256) void k_tc(const float* __restrict__ S0, const float* __restrict__ S1,
                                            const float* __restrict__ S2, const float* __restrict__ S3,
                                            u16* __restrict__ D0, u16* __restrict__ D1,
                                            u16* __restrict__ D2, u16* __restrict__ D3) {
  const float* src; u16* dst;
  switch (blockIdx.z) {
    case 0: src = S0; dst = D0; break;
    case 1: src = S1; dst = D1; break;
    case 2: src = S2; dst = D2; break;
    default: src = S3; dst = D3; break;
  }
  __shared__ __align__(16) float tl[64][65];
  const int k0 = blockIdx.x * 64, n0 = blockIdx.y * 64;
  const int tid = threadIdx.x, col = tid & 63, rq = tid >> 6;
#pragma unroll
  for (int i = 0; i < 16; i++) {
    int r = i * 4 + rq;
    tl[r][col] = src[(long)(k0 + r) * GDIM + n0 + col];
  }
  __syncthreads();
#pragma unroll
  for (int i = 0; i < 16; i++) {
    int r = i * 4 + rq;
    dst[(long)(n0 + r) * DDIM + k0 + col] = f2bf(tl[col][r]);
  }
}

// ---------- kernel 3: projection GEMM  xz = x_bf16 @ W (+bias) ----------
template <typename XZT>
__global__ __launch_bounds__(256) void k_gemm(const u16* __restrict__ A,
                                              const u16* __restrict__ BtF, const u16* __restrict__ BtB,
                                              const float* __restrict__ biasF, const float* __restrict__ biasB,
                                              XZT* __restrict__ xzF, XZT* __restrict__ xzB) {
  const u16* Bt = blockIdx.z ? BtB : BtF;
  const float* bias = blockIdx.z ? biasB : biasF;
  XZT* xz = blockIdx.z ? xzB : xzF;
  const int m0 = blockIdx.x * 128, n0 = blockIdx.y * 128;
  __shared__ __align__(16) u16 Al[128 * 32];
  __shared__ __align__(16) u16 Bl[128 * 32];
  const int tid = threadIdx.x, w = tid >> 6, l = tid & 63;
  const int wm = w & 1, wn = w >> 1;
  floatx4 acc[4][4];
#pragma unroll
  for (int i = 0; i < 4; i++)
#pragma unroll
    for (int j = 0; j < 4; j++) acc[i][j] = (floatx4)(0.0f);

  const int srow = w * 32 + (l >> 2);
  const char* Ag = (const char*)(A + (long)(m0 + srow) * DDIM) + (l & 3) * 16;
  const char* Bg = (const char*)(Bt + (long)(n0 + srow) * DDIM) + (l & 3) * 16;
  char* Asl = (char*)Al + w * 2048;
  char* Bsl = (char*)Bl + w * 2048;

  for (int kt = 0; kt < 32; kt++) {
    __syncthreads();
    async16(Ag, Asl);
    async16(Ag + 16 * 2048, Asl + 1024);
    async16(Bg, Bsl);
    async16(Bg + 16 * 2048, Bsl + 1024);
    Ag += 64; Bg += 64;
    __syncthreads();
    short8 af[4], bfr[4];
#pragma unroll
    for (int i = 0; i < 4; i++) {
      af[i]  = *(const short8*)(Al + (wm * 64 + i * 16 + (l & 15)) * 32 + (l >> 4) * 8);
      bfr[i] = *(const short8*)(Bl + (wn * 64 + i * 16 + (l & 15)) * 32 + (l >> 4) * 8);
    }
#pragma unroll
    for (int i = 0; i < 4; i++)
#pragma unroll
      for (int j = 0; j < 4; j++)
        acc[i][j] = __builtin_amdgcn_mfma_f32_16x16x32_bf16(af[i], bfr[j], acc[i][j], 0, 0, 0);
  }
  const int c = l & 15, q = l >> 4;
#pragma unroll
  for (int j = 0; j < 4; j++) {
    const int n = n0 + wn * 64 + j * 16 + c;
    const float bv = bias[n];
#pragma unroll
    for (int i = 0; i < 4; i++) {
      const long mb = (long)(m0 + wm * 64 + i * 16 + q * 4);
#pragma unroll
      for (int r = 0; r < 4; r++)
        xz[(mb + r) * GDIM + n] = f2xz<XZT>(acc[i][j][r] + bv);
    }
  }
}

// ---------- kernel 4: persistent LSTM recurrence (both directions) ----------
// 128 wgs x 512 threads: wg>>6 = dir, wd = wg&63 = 16-col group (j0 = wd*16).
// Staging (changed this round): the per-wg h sweep is ROTATED by wd*2048 B so
// the 128 wgs -- which exit the grid barrier in lockstep and previously all
// requested the SAME lines at the same instant (single-LLC-slice serialization,
// the measured ~2.3 TB/s ceiling) -- now spread uniformly across LLC slices.
// 16-deep counted-vmcnt pipeline per wave; LDS dest is a pure function of the
// rotated byte address, so the swizzled tile assembles identically (bit-exact).
template <typename XZT>
__global__ __launch_bounds__(512, 2) void k_lstm(const XZT* __restrict__ xzF, const XZT* __restrict__ xzB,
                                                 const u16* __restrict__ UtF, const u16* __restrict__ UtB,
                                                 u16* __restrict__ hbuf, float* __restrict__ out,
                                                 unsigned* __restrict__ bar) {
  extern __shared__ __align__(16) char lds[];      // 131072 B
  char* hlb = lds;                                  // h tile [64][1024] bf16, swizzled
  float* zl = (float*)lds;                          // aliases h (dead when used)

  const int wg = blockIdx.x;
  const int dir = wg >> 6;
  const int wd = wg & 63;
  const int j0 = wd * 16;
  const int tid = threadIdx.x;
  const int wv = tid >> 6, l = tid & 63;
  const int c = l & 15, q = l >> 4;
  const int g = wv & 3, rh = wv >> 2;               // gate, row-half
  const u16* Ut = dir ? UtB : UtF;
  const XZT* xz = dir ? xzB : xzF;
  u16* hb = hbuf + (size_t)dir * (4 * BH);          // 2 parities x 2 copies

  // U-slice for this wave's gate: 16 cols x K=1024 -> 32 frags = 128 VGPRs
  const int ucol = g * 1024 + j0 + c;
  short8 uf[32];
#pragma unroll
  for (int kt = 0; kt < 32; kt++)
    uf[kt] = *(const short8*)(Ut + (long)ucol * DDIM + kt * 32 + q * 8);

  // elementwise ownership: thread -> (row eb, col pair jj,jj+1) of the 16-col slice
  const int eb = tid >> 3;
  const int jj = (tid & 7) * 2;
  // zero h parity 0, both copies (agent stores: visible at LLC)
  {
    u16* hz = hb + eb * HDIM + j0 + jj;
    st_agent((unsigned*)hz, 0u);
    st_agent((unsigned*)(hz + BH), 0u);
  }
  float cs0 = 0.0f, cs1 = 0.0f;

  // xz prefetch (no h dependency; issued before the barrier each step)
  float xv0[4], xv1[4];
  auto prefetch = [&](int s) {
    const int t = dir ? (SEQT - 1 - s) : s;
#pragma unroll
    for (int r = 0; r < 4; r++) {
      xv0[r] = xz2f(xz[((long)(rh * 32 + q * 4 + r)      * SEQT + t) * GDIM + ucol]);
      xv1[r] = xz2f(xz[((long)(rh * 32 + 16 + q * 4 + r) * SEQT + t) * GDIM + ucol]);
    }
  };
  prefetch(0);

  // ds_read swizzle constants for the MFMA a-frags
  const unsigned swz = ((unsigned)(c & 7)) << 4;
  const unsigned qo = (unsigned)(q * 16);
  const unsigned rbase0 = (unsigned)((rh * 32 + c) * 2048);
  const unsigned rbase1 = rbase0 + 16 * 2048;

  // per-wg sweep rotation (2 KB-aligned, full coverage over 64 wds)
  const unsigned rot = (unsigned)(wd * 2048);

  for (int s = 0; s < SEQT; s++) {
    grid_barrier(bar, dir * 64 + wd, l, (unsigned)(s + 1));
    const int p = s & 1;
    const int t = dir ? (SEQT - 1 - s) : s;

    // ---- stage h: rotated, line-coalesced LLC reads -> swizzled LDS ----
    const u64 sbase = (u64)(hb + (size_t)(2 * p + (wd & 1)) * BH);
    short8 sv[16];
    unsigned sb[16];
#pragma unroll
    for (int j = 0; j < 16; j++) {
      sb[j] = ((unsigned)(tid * 16 + j * 8192) + rot) & 131071u;
      asm volatile("global_load_dwordx4 %0, %1, %2 sc0 sc1"
                   : "=v"(sv[j]) : "v"(sb[j]), "s"(sbase));
    }
#pragma unroll
    for (int j = 0; j < 16; j++) {
      asm volatile("s_waitcnt vmcnt(%1)" : "+v"(sv[j]) : "n"(15 - j));
      const unsigned sw = sb[j] ^ ((sb[j] >> 7) & 0x70u);   // ^((row&7)<<4)
      *(short8*)(hlb + sw) = sv[j];
    }
    __syncthreads();                     // h tile ready in LDS

    // ---- MFMA: z-tile (2 row-blocks x 16 cols of gate g) from LDS h ----
    floatx4 a0 = (floatx4)(0.0f), a1 = (floatx4)(0.0f);
#pragma unroll
    for (int kt = 0; kt < 32; kt++) {
      const unsigned off = (((unsigned)(kt * 64)) | qo) ^ swz;
      short8 af0 = *(const short8*)(hlb + rbase0 + off);
      short8 af1 = *(const short8*)(hlb + rbase1 + off);
      a0 = __builtin_amdgcn_mfma_f32_16x16x32_bf16(af0, uf[kt], a0, 0, 0, 0);
      a1 = __builtin_amdgcn_mfma_f32_16x16x32_bf16(af1, uf[kt], a1, 0, 0, 0);
    }
    __syncthreads();                     // all waves done reading h -> zl may alias

#pragma unroll
    for (int r = 0; r < 4; r++) {
      zl[(rh * 32 + q * 4 + r) * 68 + g * 16 + c]      = a0[r] + xv0[r];
      zl[(rh * 32 + 16 + q * 4 + r) * 68 + g * 16 + c] = a1[r] + xv1[r];
    }
    __syncthreads();                     // zl ready

    // ---- gates ----
    const float* zrow = zl + eb * 68;
    float zi0 = zrow[jj],      zi1 = zrow[jj + 1];
    float zf0 = zrow[16 + jj], zf1 = zrow[16 + jj + 1];
    float zg0 = zrow[32 + jj], zg1 = zrow[32 + jj + 1];
    float zo0 = zrow[48 + jj], zo1 = zrow[48 + jj + 1];
    float i0 = sigm(zi0), f0 = sigm(zf0), g0 = tanh_(zg0), o0 = sigm(zo0);
    float i1 = sigm(zi1), f1 = sigm(zf1), g1 = tanh_(zg1), o1 = sigm(zo1);
    cs0 = f0 * cs0 + i0 * g0;
    cs1 = f1 * cs1 + i1 * g1;
    float h0v = o0 * tanh_(cs0), h1v = o1 * tanh_(cs1);

    unsigned hpair = (unsigned)f2bf(h0v) | ((unsigned)f2bf(h1v) << 16);
    u16* hw = hb + (size_t)(2 * (1 - p)) * BH + eb * HDIM + j0 + jj;
    st_agent((unsigned*)hw, hpair);
    st_agent((unsigned*)(hw + BH), hpair);          // copy 1
    *(float2*)(out + (long)eb * (SEQT * 2 * HDIM) + (long)t * (2 * HDIM) + dir * HDIM + j0 + jj)
        = make_float2(h0v, h1v);

    // issue next step's xz loads now; they drain inside the next barrier
    if (s + 1 < SEQT) prefetch(s + 1);
  }
}

// ---------- host ----------
extern "C" void kernel_launch(void* const* d_in, const int* in_sizes, int n_in,
                              void* d_out, int out_size, void* d_ws, size_t ws_size,
                              hipStream_t stream) {
  const float* x   = (const float*)d_in[0];
  const float* Wf  = (const float*)d_in[1];
  const float* Uf  = (const float*)d_in[2];
  const float* bf_ = (const float*)d_in[3];
  const float* Wb  = (const float*)d_in[4];
  const float* Ub  = (const float*)d_in[5];
  const float* bb  = (const float*)d_in[6];
  float* out = (float*)d_out;
  char* ws = (char*)d_ws;

  const size_t SZ_XBF = (size_t)MROWS * DDIM * 2;        // 32 MB
  const size_t SZ_WT  = (size_t)GDIM * DDIM * 2;         // 8 MB
  const size_t SZ_H   = (size_t)2 * 4 * BH * 2;          // 2 dirs x 2 par x 2 cop = 1 MB

  size_t off = 2048;                       // [0,2048) barrier arrival words
  u16* xbf = (u16*)(ws + off); off += SZ_XBF;
  u16* WtF = (u16*)(ws + off); off += SZ_WT;
  u16* WtB = (u16*)(ws + off); off += SZ_WT;
  u16* UtF = (u16*)(ws + off); off += SZ_WT;
  u16* UtB = (u16*)(ws + off); off += SZ_WT;
  u16* hb  = (u16*)(ws + off); off += SZ_H;
  size_t xz_off = (off + 1023) & ~(size_t)1023;

  const size_t XZ_F32 = (size_t)MROWS * GDIM * 4;        // 256 MB each
  const size_t XZ_BF  = (size_t)MROWS * GDIM * 2;        // 128 MB each
  const bool fp32xz = ws_size >= xz_off + 2 * XZ_F32;

  unsigned* bar = (unsigned*)ws;
  hipMemsetAsync(bar, 0, 2048, stream);
  k_cvt_x<<<MROWS * DDIM / 1024, 256, 0, stream>>>(x, xbf);
  k_tc<<<dim3(16, 64, 4), 256, 0, stream>>>(Wf, Uf, Wb, Ub, WtF, UtF, WtB, UtB);

  if (fp32xz) {
    float* xzF = (float*)(ws + xz_off);
    float* xzB = (float*)(ws + xz_off + XZ_F32);
    k_gemm<float><<<dim3(128, 32, 2), 256, 0, stream>>>(xbf, WtF, WtB, bf_, bb, xzF, xzB);
    hipFuncSetAttribute((const void*)k_lstm<float>,
                        hipFuncAttributeMaxDynamicSharedMemorySize, 131072);
    k_lstm<float><<<128, 512, 131072, stream>>>(xzF, xzB, UtF, UtB, hb, out, bar);
  } else {
    u16* xzF = (u16*)(ws + xz_off);
    u16* xzB = (u16*)(ws + xz_off + XZ_BF);
    k_gemm<u16><<<dim3(128, 32, 2), 256, 0, stream>>>(xbf, WtF, WtB, bf_, bb, xzF, xzB);
    hipFuncSetAttribute((const void*)k_lstm<u16>,
                        hipFuncAttributeMaxDynamicSharedMemorySize, 131072);
    k_lstm<u16><<<128, 512, 131072, stream>>>(xzF, xzB, UtF, UtB, hb, out, bar);
  }
}

// Round 7
// 3021.541 us; speedup vs baseline: 1.1768x; 1.1768x over previous
//
#include <hip/hip_runtime.h>
#include <hip/hip_bf16.h>

typedef unsigned short u16;
typedef unsigned long long u64;
typedef short short8 __attribute__((ext_vector_type(8)));
typedef float floatx4 __attribute__((ext_vector_type(4)));

#define BATCH 64
#define SEQT  256
#define DDIM  1024
#define HDIM  1024
#define GDIM  4096          // 4H
#define MROWS 16384         // B*T
#define BH    (BATCH * HDIM)   // 65536 elems = 128 KB bf16

// ---------- helpers ----------
__device__ __forceinline__ u16 f2bf(float f) {
  unsigned u = __builtin_bit_cast(unsigned, f);
  u += 0x7fffu + ((u >> 16) & 1u);
  return (u16)(u >> 16);
}
__device__ __forceinline__ float bf2f(u16 v) {
  unsigned u = ((unsigned)v) << 16;
  return __builtin_bit_cast(float, u);
}
__device__ __forceinline__ float xz2f(float v) { return v; }
__device__ __forceinline__ float xz2f(u16 v) { return bf2f(v); }

template <typename T> __device__ __forceinline__ T f2xz(float v);
template <> __device__ __forceinline__ float f2xz<float>(float v) { return v; }
template <> __device__ __forceinline__ u16 f2xz<u16>(float v) { return f2bf(v); }

__device__ __forceinline__ float sigm(float x) { return 1.0f / (1.0f + __expf(-x)); }
__device__ __forceinline__ float tanh_(float x) {
  float a = __expf(2.0f * fabsf(x));      // inf-safe: a=inf -> r=1
  float r = 1.0f - 2.0f / (a + 1.0f);
  return x >= 0.0f ? r : -r;
}

__device__ __forceinline__ void async16(const void* g, void* l) {
  __builtin_amdgcn_global_load_lds(
      (const __attribute__((address_space(1))) unsigned int*)g,
      (__attribute__((address_space(3))) unsigned int*)l, 16, 0, 0);
}

// agent-scope (LLC-coherent) store for the h hand-off (write-around local L2,
// lands at the memory-side LLC = the coherence point)
__device__ __forceinline__ void st_agent(unsigned* p, unsigned v) {
  __hip_atomic_store(p, v, __ATOMIC_RELAXED, __HIP_MEMORY_SCOPE_AGENT);
}

// Fence-free grid barrier (128 wgs total: words [0,64) dir0, [64,128) dir1).
__device__ __forceinline__ void grid_barrier(unsigned* bar_, int wdg, int l, unsigned epoch) {
  __syncthreads();
  if (threadIdx.x == 0)
    __hip_atomic_store(bar_ + wdg, epoch, __ATOMIC_RELAXED, __HIP_MEMORY_SCOPE_AGENT);
  if (threadIdx.x < 64) {
    unsigned a, b;
    do {
      __builtin_amdgcn_s_sleep(2);
      a = __hip_atomic_load(bar_ + l,      __ATOMIC_RELAXED, __HIP_MEMORY_SCOPE_AGENT);
      b = __hip_atomic_load(bar_ + 64 + l, __ATOMIC_RELAXED, __HIP_MEMORY_SCOPE_AGENT);
    } while (!__all(a >= epoch && b >= epoch));
  }
  __syncthreads();
}

// ---------- kernel 1: x fp32 -> bf16 ----------
__global__ __launch_bounds__(256) void k_cvt_x(const float* __restrict__ in,
                                               u16* __restrict__ out) {
  long i = ((long)blockIdx.x * 256 + threadIdx.x) * 4;
  float4 v = *(const float4*)(in + i);
  u16 o0 = f2bf(v.x), o1 = f2bf(v.y), o2 = f2bf(v.z), o3 = f2bf(v.w);
  unsigned lo = (unsigned)o0 | ((unsigned)o1 << 16);
  unsigned hi = (unsigned)o2 | ((unsigned)o3 << 16);
  uint2 p; p.x = lo; p.y = hi;
  *(uint2*)(out + i) = p;
}

// ---------- kernel 2: transpose-convert [1024][4096] fp32 -> [4096][1024] bf16 ----------
__global__ __launch_bounds__(256) void k_tc(const float* __restrict__ S0, const float* __restrict__ S1,
                                            const float* __restrict__ S2, const float* __restrict__ S3,
                                            u16* __restrict__ D0, u16* __restrict__ D1,
                                            u16* __restrict__ D2, u16* __restrict__ D3) {
  const float* src; u16* dst;
  switch (blockIdx.z) {
    case 0: src = S0; dst = D0; break;
    case 1: src = S1; dst = D1; break;
    case 2: src = S2; dst = D2; break;
    default: src = S3; dst = D3; break;
  }
  __shared__ __align__(16) float tl[64][65];
  const int k0 = blockIdx.x * 64, n0 = blockIdx.y * 64;
  const int tid = threadIdx.x, col = tid & 63, rq = tid >> 6;
#pragma unroll
  for (int i = 0; i < 16; i++) {
    int r = i * 4 + rq;
    tl[r][col] = src[(long)(k0 + r) * GDIM + n0 + col];
  }
  __syncthreads();
#pragma unroll
  for (int i = 0; i < 16; i++) {
    int r = i * 4 + rq;
    dst[(long)(n0 + r) * DDIM + k0 + col] = f2bf(tl[col][r]);
  }
}

// ---------- kernel 3: projection GEMM  xz = x_bf16 @ W (+bias) ----------
template <typename XZT>
__global__ __launch_bounds__(256) void k_gemm(const u16* __restrict__ A,
                                              const u16* __restrict__ BtF, const u16* __restrict__ BtB,
                                              const float* __restrict__ biasF, const float* __restrict__ biasB,
                                              XZT* __restrict__ xzF, XZT* __restrict__ xzB) {
  const u16* Bt = blockIdx.z ? BtB : BtF;
  const float* bias = blockIdx.z ? biasB : biasF;
  XZT* xz = blockIdx.z ? xzB : xzF;
  const int m0 = blockIdx.x * 128, n0 = blockIdx.y * 128;
  __shared__ __align__(16) u16 Al[128 * 32];
  __shared__ __align__(16) u16 Bl[128 * 32];
  const int tid = threadIdx.x, w = tid >> 6, l = tid & 63;
  const int wm = w & 1, wn = w >> 1;
  floatx4 acc[4][4];
#pragma unroll
  for (int i = 0; i < 4; i++)
#pragma unroll
    for (int j = 0; j < 4; j++) acc[i][j] = (floatx4)(0.0f);

  const int srow = w * 32 + (l >> 2);
  const char* Ag = (const char*)(A + (long)(m0 + srow) * DDIM) + (l & 3) * 16;
  const char* Bg = (const char*)(Bt + (long)(n0 + srow) * DDIM) + (l & 3) * 16;
  char* Asl = (char*)Al + w * 2048;
  char* Bsl = (char*)Bl + w * 2048;

  for (int kt = 0; kt < 32; kt++) {
    __syncthreads();
    async16(Ag, Asl);
    async16(Ag + 16 * 2048, Asl + 1024);
    async16(Bg, Bsl);
    async16(Bg + 16 * 2048, Bsl + 1024);
    Ag += 64; Bg += 64;
    __syncthreads();
    short8 af[4], bfr[4];
#pragma unroll
    for (int i = 0; i < 4; i++) {
      af[i]  = *(const short8*)(Al + (wm * 64 + i * 16 + (l & 15)) * 32 + (l >> 4) * 8);
      bfr[i] = *(const short8*)(Bl + (wn * 64 + i * 16 + (l & 15)) * 32 + (l >> 4) * 8);
    }
#pragma unroll
    for (int i = 0; i < 4; i++)
#pragma unroll
      for (int j = 0; j < 4; j++)
        acc[i][j] = __builtin_amdgcn_mfma_f32_16x16x32_bf16(af[i], bfr[j], acc[i][j], 0, 0, 0);
  }
  const int c = l & 15, q = l >> 4;
#pragma unroll
  for (int j = 0; j < 4; j++) {
    const int n = n0 + wn * 64 + j * 16 + c;
    const float bv = bias[n];
#pragma unroll
    for (int i = 0; i < 4; i++) {
      const long mb = (long)(m0 + wm * 64 + i * 16 + q * 4);
#pragma unroll
      for (int r = 0; r < 4; r++)
        xz[(mb + r) * GDIM + n] = f2xz<XZT>(acc[i][j][r] + bv);
    }
  }
}

// ---------- kernel 4: persistent LSTM recurrence (both directions) ----------
// 128 wgs x 512 threads: wg>>6 = dir, wd = wg&63 = 16-col group (j0 = wd*16).
//
// h hand-off (changed this round): FRESH-ADDRESS cached broadcast.
// h[s] lives in a 257-slot history buffer hist[dir][s][64][1024] bf16.
// Producers: agent-scope stores to slot s+1 (write-around, land at LLC,
// drained before the barrier flag). Readers: PLAIN CACHED global_load_lds
// from slot s -- slot s was never touched by any XCD earlier in this launch,
// so the L2 fill from LLC is guaranteed fresh: no fences, no invalidates.
// Per XCD: first toucher misses to LLC (128 KB/step, MSHR-merged), the other
// ~15 wgs hit the XCD's L2 (4.3 TB/s each). This moves the h broadcast off
// the ~2-3 TB/s sc0sc1 service path (the measured R0/R2/R5/R6 wall).
// Staging uses pre-swizzled SOURCE addresses (m173): the XOR swizzle only
// permutes 16B units within a 128B line, so coalescing is intact and the LDS
// image is bit-identical to R5's (XOR involution). Cross-launch staleness is
// covered by the dispatch-boundary acquire (same mechanism that makes the
// k_gemm -> k_lstm xz hand-off correct).
template <typename XZT>
__global__ __launch_bounds__(512, 2) void k_lstm(const XZT* __restrict__ xzF, const XZT* __restrict__ xzB,
                                                 const u16* __restrict__ UtF, const u16* __restrict__ UtB,
                                                 u16* __restrict__ hist, float* __restrict__ out,
                                                 unsigned* __restrict__ bar) {
  extern __shared__ __align__(16) char lds[];      // 131072 B
  char* hlb = lds;                                  // h tile [64][1024] bf16, swizzled
  float* zl = (float*)lds;                          // aliases h (dead when used)

  const int wg = blockIdx.x;
  const int dir = wg >> 6;
  const int wd = wg & 63;
  const int j0 = wd * 16;
  const int tid = threadIdx.x;
  const int wv = tid >> 6, l = tid & 63;
  const int c = l & 15, q = l >> 4;
  const int g = wv & 3, rh = wv >> 2;               // gate, row-half
  const u16* Ut = dir ? UtB : UtF;
  const XZT* xz = dir ? xzB : xzF;
  u16* hd = hist + (size_t)dir * ((SEQT + 1) * (size_t)BH);   // 257 slots

  // U-slice for this wave's gate: 16 cols x K=1024 -> 32 frags = 128 VGPRs
  const int ucol = g * 1024 + j0 + c;
  short8 uf[32];
#pragma unroll
  for (int kt = 0; kt < 32; kt++)
    uf[kt] = *(const short8*)(Ut + (long)ucol * DDIM + kt * 32 + q * 8);

  // elementwise ownership: thread -> (row eb, col pair jj,jj+1) of the 16-col slice
  const int eb = tid >> 3;
  const int jj = (tid & 7) * 2;
  // zero h slot 0 (agent store: visible at LLC, never dirty in any L2)
  st_agent((unsigned*)(hd + eb * HDIM + j0 + jj), 0u);
  float cs0 = 0.0f, cs1 = 0.0f;

  // xz prefetch (no h dependency; issued before the barrier each step)
  float xv0[4], xv1[4];
  auto prefetch = [&](int s) {
    const int t = dir ? (SEQT - 1 - s) : s;
#pragma unroll
    for (int r = 0; r < 4; r++) {
      xv0[r] = xz2f(xz[((long)(rh * 32 + q * 4 + r)      * SEQT + t) * GDIM + ucol]);
      xv1[r] = xz2f(xz[((long)(rh * 32 + 16 + q * 4 + r) * SEQT + t) * GDIM + ucol]);
    }
  };
  prefetch(0);

  // ds_read swizzle constants for the MFMA a-frags (unchanged from R5, proven)
  const unsigned swz = ((unsigned)(c & 7)) << 4;
  const unsigned qo = (unsigned)(q * 16);
  const unsigned rbase0 = (unsigned)((rh * 32 + c) * 2048);
  const unsigned rbase1 = rbase0 + 16 * 2048;

  for (int s = 0; s < SEQT; s++) {
    grid_barrier(bar, dir * 64 + wd, l, (unsigned)(s + 1));
    const int t = dir ? (SEQT - 1 - s) : s;

    // ---- stage h slot s: cached global_load_lds, pre-swizzled source ----
    // LDS image: hlb[m] = hsrc[m ^ f(m)], f(m) = (m>>7)&0x70 -- identical to
    // R5's write-side-swizzled image (involution), so MFMA reads are unchanged.
    const char* hsrc = (const char*)(hd + (size_t)s * BH);
#pragma unroll
    for (int j = 0; j < 16; j++) {
      const unsigned lin = (unsigned)(tid * 16 + j * 8192);
      const unsigned src = lin ^ ((lin >> 7) & 0x70u);
      async16(hsrc + src, hlb + (unsigned)(wv * 1024 + j * 8192));
    }
    __syncthreads();                     // h tile ready in LDS (vmcnt drained)

    // ---- MFMA: z-tile (2 row-blocks x 16 cols of gate g) from LDS h ----
    floatx4 a0 = (floatx4)(0.0f), a1 = (floatx4)(0.0f);
#pragma unroll
    for (int kt = 0; kt < 32; kt++) {
      const unsigned off = (((unsigned)(kt * 64)) | qo) ^ swz;
      short8 af0 = *(const short8*)(hlb + rbase0 + off);
      short8 af1 = *(const short8*)(hlb + rbase1 + off);
      a0 = __builtin_amdgcn_mfma_f32_16x16x32_bf16(af0, uf[kt], a0, 0, 0, 0);
      a1 = __builtin_amdgcn_mfma_f32_16x16x32_bf16(af1, uf[kt], a1, 0, 0, 0);
    }
    __syncthreads();                     // all waves done reading h -> zl may alias

#pragma unroll
    for (int r = 0; r < 4; r++) {
      zl[(rh * 32 + q * 4 + r) * 68 + g * 16 + c]      = a0[r] + xv0[r];
      zl[(rh * 32 + 16 + q * 4 + r) * 68 + g * 16 + c] = a1[r] + xv1[r];
    }
    __syncthreads();                     // zl ready

    // ---- gates ----
    const float* zrow = zl + eb * 68;
    float zi0 = zrow[jj],      zi1 = zrow[jj + 1];
    float zf0 = zrow[16 + jj], zf1 = zrow[16 + jj + 1];
    float zg0 = zrow[32 + jj], zg1 = zrow[32 + jj + 1];
    float zo0 = zrow[48 + jj], zo1 = zrow[48 + jj + 1];
    float i0 = sigm(zi0), f0 = sigm(zf0), g0 = tanh_(zg0), o0 = sigm(zo0);
    float i1 = sigm(zi1), f1 = sigm(zf1), g1 = tanh_(zg1), o1 = sigm(zo1);
    cs0 = f0 * cs0 + i0 * g0;
    cs1 = f1 * cs1 + i1 * g1;
    float h0v = o0 * tanh_(cs0), h1v = o1 * tanh_(cs1);

    unsigned hpair = (unsigned)f2bf(h0v) | ((unsigned)f2bf(h1v) << 16);
    st_agent((unsigned*)(hd + (size_t)(s + 1) * BH + eb * HDIM + j0 + jj), hpair);
    *(float2*)(out + (long)eb * (SEQT * 2 * HDIM) + (long)t * (2 * HDIM) + dir * HDIM + j0 + jj)
        = make_float2(h0v, h1v);

    // issue next step's xz loads now; they drain inside the next barrier
    if (s + 1 < SEQT) prefetch(s + 1);
  }
}

// ---------- host ----------
extern "C" void kernel_launch(void* const* d_in, const int* in_sizes, int n_in,
                              void* d_out, int out_size, void* d_ws, size_t ws_size,
                              hipStream_t stream) {
  const float* x   = (const float*)d_in[0];
  const float* Wf  = (const float*)d_in[1];
  const float* Uf  = (const float*)d_in[2];
  const float* bf_ = (const float*)d_in[3];
  const float* Wb  = (const float*)d_in[4];
  const float* Ub  = (const float*)d_in[5];
  const float* bb  = (const float*)d_in[6];
  float* out = (float*)d_out;
  char* ws = (char*)d_ws;

  const size_t SZ_XBF  = (size_t)MROWS * DDIM * 2;             // 32 MB
  const size_t SZ_WT   = (size_t)GDIM * DDIM * 2;              // 8 MB
  const size_t SZ_HIST = (size_t)2 * (SEQT + 1) * BH * 2;      // 64.25 MB

  size_t off = 2048;                       // [0,2048) barrier arrival words
  u16* xbf  = (u16*)(ws + off); off += SZ_XBF;
  u16* WtF  = (u16*)(ws + off); off += SZ_WT;
  u16* WtB  = (u16*)(ws + off); off += SZ_WT;
  u16* UtF  = (u16*)(ws + off); off += SZ_WT;
  u16* UtB  = (u16*)(ws + off); off += SZ_WT;
  u16* hist = (u16*)(ws + off); off += SZ_HIST;
  size_t xz_off = (off + 1023) & ~(size_t)1023;

  const size_t XZ_F32 = (size_t)MROWS * GDIM * 4;        // 256 MB each
  const size_t XZ_BF  = (size_t)MROWS * GDIM * 2;        // 128 MB each
  const bool fp32xz = ws_size >= xz_off + 2 * XZ_F32;

  unsigned* bar = (unsigned*)ws;
  hipMemsetAsync(bar, 0, 2048, stream);
  k_cvt_x<<<MROWS * DDIM / 1024, 256, 0, stream>>>(x, xbf);
  k_tc<<<dim3(16, 64, 4), 256, 0, stream>>>(Wf, Uf, Wb, Ub, WtF, UtF, WtB, UtB);

  if (fp32xz) {
    float* xzF = (float*)(ws + xz_off);
    float* xzB = (float*)(ws + xz_off + XZ_F32);
    k_gemm<float><<<dim3(128, 32, 2), 256, 0, stream>>>(xbf, WtF, WtB, bf_, bb, xzF, xzB);
    hipFuncSetAttribute((const void*)k_lstm<float>,
                        hipFuncAttributeMaxDynamicSharedMemorySize, 131072);
    k_lstm<float><<<128, 512, 131072, stream>>>(xzF, xzB, UtF, UtB, hist, out, bar);
  } else {
    u16* xzF = (u16*)(ws + xz_off);
    u16* xzB = (u16*)(ws + xz_off + XZ_BF);
    k_gemm<u16><<<dim3(128, 32, 2), 256, 0, stream>>>(xbf, WtF, WtB, bf_, bb, xzF, xzB);
    hipFuncSetAttribute((const void*)k_lstm<u16>,
                        hipFuncAttributeMaxDynamicSharedMemorySize, 131072);
    k_lstm<u16><<<128, 512, 131072, stream>>>(xzF, xzB, UtF, UtB, hist, out, bar);
  }
}